// Round 1
// baseline (2731.311 us; speedup 1.0000x reference)
//
#include <hip/hip_runtime.h>

#define N_NODES 50000
#define N_EDGES 800000
#define IN_DIM  64
#define EDGE_DIM 16
#define HID     128
#define NLAYERS 3
#define NGRAPH  128
#define EPS     1e-5f
#define EPB     2   // edges per block in edge kernel

// ---------------- init: zero cnt + pool ----------------
__global__ void k_init(float* __restrict__ cnt, float* __restrict__ pool) {
    int i = blockIdx.x * blockDim.x + threadIdx.x;
    if (i < NGRAPH) cnt[i] = 0.0f;
    if (i < NGRAPH * HID) pool[i] = 0.0f;
}

// ---------------- per-graph node counts ----------------
__global__ void k_count(const int* __restrict__ batch, float* __restrict__ cnt) {
    int i = blockIdx.x * blockDim.x + threadIdx.x;
    if (i < N_NODES) atomicAdd(&cnt[batch[i]], 1.0f);
}

// ---------------- input encoder: one node per block ----------------
__global__ __launch_bounds__(HID) void k_encoder(
    const float* __restrict__ x,
    const float* __restrict__ lw1, const float* __restrict__ lb1,
    const float* __restrict__ lw2, const float* __restrict__ lb2,
    const float* __restrict__ pw1, const float* __restrict__ pb1,
    const float* __restrict__ pw2, const float* __restrict__ pb2,
    float* __restrict__ H) {
    __shared__ float xs[IN_DIM];
    __shared__ float h1[HID];
    int n = blockIdx.x;
    int t = threadIdx.x;
    if (t < IN_DIM) xs[t] = x[n * IN_DIM + t];
    __syncthreads();
    // protein flag is last feature; block-uniform -> no divergence, halves work
    bool prot = xs[IN_DIM - 1] > 0.5f;
    const float* w1 = prot ? pw1 : lw1;
    const float* b1 = prot ? pb1 : lb1;
    const float* w2 = prot ? pw2 : lw2;
    const float* b2 = prot ? pb2 : lb2;
    float acc = b1[t];
    #pragma unroll 4
    for (int k = 0; k < IN_DIM; ++k) acc = fmaf(xs[k], w1[k * HID + t], acc);
    h1[t] = fmaxf(acc, 0.0f);
    __syncthreads();
    float acc2 = b2[t];
    #pragma unroll 4
    for (int k = 0; k < HID; ++k) acc2 = fmaf(h1[k], w2[k * HID + t], acc2);
    H[n * HID + t] = fmaxf(acc2, 0.0f);
}

// ---------------- per-layer prep: A = H copy + zero moment buffers ----------------
__global__ void k_prep(const float4* __restrict__ H4, float4* __restrict__ A4,
                       float* __restrict__ gsum, float* __restrict__ gsq) {
    int i = blockIdx.x * blockDim.x + threadIdx.x;
    if (i < N_NODES * HID / 4) A4[i] = H4[i];
    if (i < NGRAPH * HID) { gsum[i] = 0.0f; gsq[i] = 0.0f; }
}

// ---------------- edge message + scatter: one edge per 128-thread group ----------------
__global__ __launch_bounds__(EPB * HID) void k_edge(
    const int* __restrict__ srcs, const int* __restrict__ dsts,
    const float* __restrict__ ea,
    const float* __restrict__ ew, const float* __restrict__ eb,
    const float* __restrict__ H, float* __restrict__ A) {
    int g = threadIdx.x >> 7;          // group within block
    int t = threadIdx.x & (HID - 1);   // feature
    int e = blockIdx.x * EPB + g;
    if (e >= N_EDGES) return;
    int src = srcs[e];
    int dst = dsts[e];
    const float* eap = ea + (long long)e * EDGE_DIM;  // one 64B cacheline per edge
    float acc = eb[t];
    #pragma unroll
    for (int k = 0; k < EDGE_DIM; ++k) acc = fmaf(eap[k], ew[k * HID + t], acc);
    float msg = fmaxf(H[src * HID + t] + acc, 0.0f);
    atomicAdd(&A[dst * HID + t], msg);
}

// ---------------- node MLP + fused per-graph moment accumulation ----------------
__global__ __launch_bounds__(HID) void k_mlp(
    const float* __restrict__ A, const int* __restrict__ batch,
    const float* __restrict__ w1, const float* __restrict__ b1,
    const float* __restrict__ w2, const float* __restrict__ b2,
    float* __restrict__ H, float* __restrict__ gsum, float* __restrict__ gsq) {
    __shared__ float as[HID];
    __shared__ float h1[HID];
    int n = blockIdx.x;
    int t = threadIdx.x;
    as[t] = A[n * HID + t];
    __syncthreads();
    float acc = b1[t];
    #pragma unroll 4
    for (int k = 0; k < HID; ++k) acc = fmaf(as[k], w1[k * HID + t], acc);
    h1[t] = fmaxf(acc, 0.0f);
    __syncthreads();
    float acc2 = b2[t];
    #pragma unroll 4
    for (int k = 0; k < HID; ++k) acc2 = fmaf(h1[k], w2[k * HID + t], acc2);
    H[n * HID + t] = acc2;   // pre-norm (no relu yet)
    int bg = batch[n];
    atomicAdd(&gsum[bg * HID + t], acc2);
    atomicAdd(&gsq[bg * HID + t], acc2 * acc2);
}

// ---------------- GraphNorm stats -> per-(graph,feat) scale/offset ----------------
// hc = h - mean*ms ; var = E[h^2] - mean^2 * ms * (2 - ms)
// out = gw * hc * rsqrt(var+eps) + gb = h*sc + of
__global__ __launch_bounds__(HID) void k_stats(
    const float* __restrict__ gsum, const float* __restrict__ gsq,
    const float* __restrict__ cnt,
    const float* __restrict__ gw, const float* __restrict__ gb,
    const float* __restrict__ gms,
    float* __restrict__ sc, float* __restrict__ of) {
    int g = blockIdx.x;
    int t = threadIdx.x;
    float c = fmaxf(cnt[g], 1.0f);
    float mean = gsum[g * HID + t] / c;
    float msq  = gsq[g * HID + t] / c;
    float ms = gms[t];
    float var = msq - mean * mean * ms * (2.0f - ms);
    var = fmaxf(var, 0.0f);
    float istd = rsqrtf(var + EPS);
    float s = gw[t] * istd;
    sc[g * HID + t] = s;
    of[g * HID + t] = gb[t] - s * mean * ms;
}

// ---------------- normalize + relu (+ fused global_add_pool on last layer) ----------------
__global__ void k_norm(float* __restrict__ H, const int* __restrict__ batch,
                       const float* __restrict__ sc, const float* __restrict__ of,
                       float* __restrict__ pool, int accumulate) {
    int i = blockIdx.x * blockDim.x + threadIdx.x;
    if (i >= N_NODES * HID) return;
    int n = i >> 7;
    int t = i & (HID - 1);
    int g = batch[n];
    float v = fmaxf(H[i] * sc[g * HID + t] + of[g * HID + t], 0.0f);
    H[i] = v;
    if (accumulate) atomicAdd(&pool[g * HID + t], v);
}

// ---------------- output head: one graph per block ----------------
__global__ __launch_bounds__(HID) void k_head(
    const float* __restrict__ pool,
    const float* __restrict__ fw1, const float* __restrict__ fb1,
    const float* __restrict__ fw2, const float* __restrict__ fb2,
    float* __restrict__ out) {
    __shared__ float ps[HID];
    __shared__ float red[2];
    int g = blockIdx.x;
    int t = threadIdx.x;
    ps[t] = pool[g * HID + t];
    __syncthreads();
    float acc = fb1[t];
    #pragma unroll 4
    for (int k = 0; k < HID; ++k) acc = fmaf(ps[k], fw1[k * HID + t], acc);
    float p = fmaxf(acc, 0.0f) * fw2[t];
    // wave-64 shuffle reduction
    #pragma unroll
    for (int off = 32; off > 0; off >>= 1) p += __shfl_down(p, off, 64);
    if ((t & 63) == 0) red[t >> 6] = p;
    __syncthreads();
    if (t == 0) out[g] = red[0] + red[1] + fb2[0];
}

extern "C" void kernel_launch(void* const* d_in, const int* in_sizes, int n_in,
                              void* d_out, int out_size, void* d_ws, size_t ws_size,
                              hipStream_t stream) {
    const float* x     = (const float*)d_in[0];
    const int*   ei    = (const int*)d_in[1];
    const float* ea    = (const float*)d_in[2];
    const int*   batch = (const int*)d_in[3];
    const float* lw1 = (const float*)d_in[4];
    const float* lb1 = (const float*)d_in[5];
    const float* lw2 = (const float*)d_in[6];
    const float* lb2 = (const float*)d_in[7];
    const float* pw1 = (const float*)d_in[8];
    const float* pb1 = (const float*)d_in[9];
    const float* pw2 = (const float*)d_in[10];
    const float* pb2 = (const float*)d_in[11];
    const float* ew  = (const float*)d_in[12];
    const float* eb  = (const float*)d_in[13];
    const float* nw1 = (const float*)d_in[14];
    const float* nb1 = (const float*)d_in[15];
    const float* nw2 = (const float*)d_in[16];
    const float* nb2 = (const float*)d_in[17];
    const float* gw  = (const float*)d_in[18];
    const float* gb  = (const float*)d_in[19];
    const float* gms = (const float*)d_in[20];
    const float* fw1 = (const float*)d_in[21];
    const float* fb1 = (const float*)d_in[22];
    const float* fw2 = (const float*)d_in[23];
    const float* fb2 = (const float*)d_in[24];
    float* out = (float*)d_out;

    float* ws   = (float*)d_ws;
    float* H    = ws;                        // 6.4M floats
    float* A    = H    + N_NODES * HID;      // 6.4M floats
    float* gsum = A    + N_NODES * HID;      // 16384
    float* gsq  = gsum + NGRAPH * HID;       // 16384
    float* sc   = gsq  + NGRAPH * HID;       // 16384
    float* of   = sc   + NGRAPH * HID;       // 16384
    float* pool = of   + NGRAPH * HID;       // 16384
    float* cnt  = pool + NGRAPH * HID;       // 128

    const int* srcs = ei;
    const int* dsts = ei + N_EDGES;

    k_init<<<(NGRAPH * HID + 255) / 256, 256, 0, stream>>>(cnt, pool);
    k_count<<<(N_NODES + 255) / 256, 256, 0, stream>>>(batch, cnt);
    k_encoder<<<N_NODES, HID, 0, stream>>>(x, lw1, lb1, lw2, lb2,
                                           pw1, pb1, pw2, pb2, H);
    for (int l = 0; l < NLAYERS; ++l) {
        k_prep<<<(N_NODES * HID / 4 + 255) / 256, 256, 0, stream>>>(
            (const float4*)H, (float4*)A, gsum, gsq);
        k_edge<<<(N_EDGES + EPB - 1) / EPB, EPB * HID, 0, stream>>>(
            srcs, dsts, ea, ew + l * EDGE_DIM * HID, eb + l * HID, H, A);
        k_mlp<<<N_NODES, HID, 0, stream>>>(
            A, batch, nw1 + l * HID * HID, nb1 + l * HID,
            nw2 + l * HID * HID, nb2 + l * HID, H, gsum, gsq);
        k_stats<<<NGRAPH, HID, 0, stream>>>(gsum, gsq, cnt,
                                            gw + l * HID, gb + l * HID, gms + l * HID,
                                            sc, of);
        k_norm<<<(N_NODES * HID + 255) / 256, 256, 0, stream>>>(
            H, batch, sc, of, pool, (l == NLAYERS - 1) ? 1 : 0);
    }
    k_head<<<NGRAPH, HID, 0, stream>>>(pool, fw1, fb1, fw2, fb2, out);
}

// Round 2
// 1288.949 us; speedup vs baseline: 2.1190x; 2.1190x over previous
//
#include <hip/hip_runtime.h>

#define N_NODES 50000
#define N_EDGES 800000
#define IN_DIM  64
#define EDGE_DIM 16
#define HID     128
#define NLAYERS 3
#define NGRAPH  128
#define EPS     1e-5f

// ==================== init: zero small buffers + CSR counters ====================
__global__ void k_init(int* __restrict__ row_cnt, float* __restrict__ cnt,
                       float* __restrict__ pool, float* __restrict__ gsum,
                       float* __restrict__ gsq) {
    int i = blockIdx.x * blockDim.x + threadIdx.x;
    if (i < N_NODES) row_cnt[i] = 0;
    if (i < NGRAPH * HID) { pool[i] = 0.0f; gsum[i] = 0.0f; gsq[i] = 0.0f; }
    if (i < NGRAPH) cnt[i] = 0.0f;
}

// ==================== per-graph node counts ====================
__global__ void k_count(const int* __restrict__ batch, float* __restrict__ cnt) {
    int i = blockIdx.x * blockDim.x + threadIdx.x;
    if (i < N_NODES) atomicAdd(&cnt[batch[i]], 1.0f);
}

// ==================== CSR build: histogram of dst ====================
__global__ void k_hist(const int* __restrict__ dsts, int* __restrict__ row_cnt) {
    int e = blockIdx.x * blockDim.x + threadIdx.x;
    if (e < N_EDGES) atomicAdd(&row_cnt[dsts[e]], 1);
}

// ==================== scan phase 1: per-512-chunk sums ====================
__global__ __launch_bounds__(256) void k_scan1(const int* __restrict__ row_cnt,
                                               int* __restrict__ partial) {
    __shared__ int s[256];
    int t = threadIdx.x, b = blockIdx.x;
    int i0 = b * 512 + t;
    int v = 0;
    if (i0 < N_NODES) v += row_cnt[i0];
    if (i0 + 256 < N_NODES) v += row_cnt[i0 + 256];
    s[t] = v; __syncthreads();
    for (int off = 128; off > 0; off >>= 1) {
        if (t < off) s[t] += s[t + off];
        __syncthreads();
    }
    if (t == 0) partial[b] = s[0];
}

// ==================== scan phase 2: exclusive scan of 98 partials ====================
#define NCHUNK 98
__global__ __launch_bounds__(128) void k_scan2(int* __restrict__ partial) {
    __shared__ int s[128];
    int t = threadIdx.x;
    int v = (t < NCHUNK) ? partial[t] : 0;
    s[t] = v; __syncthreads();
    for (int off = 1; off < 128; off <<= 1) {
        int x = (t >= off) ? s[t - off] : 0;
        __syncthreads();
        s[t] += x;
        __syncthreads();
    }
    partial[t] = s[t] - v;   // exclusive
}

// ==================== scan phase 3: per-chunk exclusive scan -> row_start/row_fill ====================
__global__ __launch_bounds__(512) void k_scan3(const int* __restrict__ row_cnt,
                                               const int* __restrict__ partial,
                                               int* __restrict__ row_start,
                                               int* __restrict__ row_fill) {
    __shared__ int s[512];
    int t = threadIdx.x, b = blockIdx.x;
    int i = b * 512 + t;
    int v = (i < N_NODES) ? row_cnt[i] : 0;
    s[t] = v; __syncthreads();
    for (int off = 1; off < 512; off <<= 1) {
        int x = (t >= off) ? s[t - off] : 0;
        __syncthreads();
        s[t] += x;
        __syncthreads();
    }
    int excl = s[t] - v + partial[b];
    if (i < N_NODES) { row_start[i] = excl; row_fill[i] = excl; }
}

// ==================== CSR fill ====================
__global__ void k_fill(const int* __restrict__ dsts, int* __restrict__ row_fill,
                       int* __restrict__ csr_eid) {
    int e = blockIdx.x * blockDim.x + threadIdx.x;
    if (e < N_EDGES) {
        int p = atomicAdd(&row_fill[dsts[e]], 1);
        csr_eid[p] = e;
    }
}

// ==================== input encoder: 4 nodes/block, both paths, select at end ====================
#define ENC_N 4
__global__ __launch_bounds__(HID) void k_encoder(
    const float* __restrict__ x,
    const float* __restrict__ lw1, const float* __restrict__ lb1,
    const float* __restrict__ lw2, const float* __restrict__ lb2,
    const float* __restrict__ pw1, const float* __restrict__ pb1,
    const float* __restrict__ pw2, const float* __restrict__ pb2,
    float* __restrict__ H) {
    __shared__ float h1l[ENC_N * HID];
    __shared__ float h1p[ENC_N * HID];
    int n0 = blockIdx.x * ENC_N;
    int t = threadIdx.x;
    float accl[ENC_N], accp[ENC_N];
    float bl = lb1[t], bp = pb1[t];
    #pragma unroll
    for (int i = 0; i < ENC_N; ++i) { accl[i] = bl; accp[i] = bp; }
    for (int k4 = 0; k4 < IN_DIM; k4 += 4) {
        float4 a[ENC_N];
        #pragma unroll
        for (int i = 0; i < ENC_N; ++i)
            a[i] = *(const float4*)&x[(n0 + i) * IN_DIM + k4];
        #pragma unroll
        for (int kk = 0; kk < 4; ++kk) {
            float wl = lw1[(k4 + kk) * HID + t];
            float wp = pw1[(k4 + kk) * HID + t];
            #pragma unroll
            for (int i = 0; i < ENC_N; ++i) {
                float c = ((const float*)&a[i])[kk];
                accl[i] = fmaf(c, wl, accl[i]);
                accp[i] = fmaf(c, wp, accp[i]);
            }
        }
    }
    #pragma unroll
    for (int i = 0; i < ENC_N; ++i) {
        h1l[i * HID + t] = fmaxf(accl[i], 0.0f);
        h1p[i * HID + t] = fmaxf(accp[i], 0.0f);
    }
    __syncthreads();
    float bl2 = lb2[t], bp2 = pb2[t];
    #pragma unroll
    for (int i = 0; i < ENC_N; ++i) { accl[i] = bl2; accp[i] = bp2; }
    for (int k4 = 0; k4 < HID; k4 += 4) {
        float4 hl[ENC_N], hp[ENC_N];
        #pragma unroll
        for (int i = 0; i < ENC_N; ++i) {
            hl[i] = *(const float4*)&h1l[i * HID + k4];
            hp[i] = *(const float4*)&h1p[i * HID + k4];
        }
        #pragma unroll
        for (int kk = 0; kk < 4; ++kk) {
            float wl = lw2[(k4 + kk) * HID + t];
            float wp = pw2[(k4 + kk) * HID + t];
            #pragma unroll
            for (int i = 0; i < ENC_N; ++i) {
                accl[i] = fmaf(((const float*)&hl[i])[kk], wl, accl[i]);
                accp[i] = fmaf(((const float*)&hp[i])[kk], wp, accp[i]);
            }
        }
    }
    #pragma unroll
    for (int i = 0; i < ENC_N; ++i) {
        bool prot = x[(n0 + i) * IN_DIM + (IN_DIM - 1)] > 0.5f;
        float v = prot ? accp[i] : accl[i];
        H[(n0 + i) * HID + t] = fmaxf(v, 0.0f);
    }
}

// ==================== edge gather: one dst node per block, ew column in registers ====================
__global__ __launch_bounds__(HID) void k_gather(
    const int* __restrict__ srcs, const float* __restrict__ ea,
    const int* __restrict__ row_start, const int* __restrict__ row_fill,
    const int* __restrict__ csr_eid,
    const float* __restrict__ ew, const float* __restrict__ eb,
    const float* __restrict__ H, float* __restrict__ A) {
    int n = blockIdx.x;
    int t = threadIdx.x;
    float ewc[EDGE_DIM];
    #pragma unroll
    for (int k = 0; k < EDGE_DIM; ++k) ewc[k] = ew[k * HID + t];
    float ebv = eb[t];
    float acc = H[n * HID + t];
    int p = row_start[n], pe = row_fill[n];
    for (; p < pe; ++p) {
        int eid = csr_eid[p];
        int src = srcs[eid];
        const float4* ea4 = (const float4*)(ea + (long long)eid * EDGE_DIM);
        float4 a0 = ea4[0], a1 = ea4[1], a2 = ea4[2], a3 = ea4[3];
        float hs = H[src * HID + t];
        float lin = ebv;
        lin = fmaf(a0.x, ewc[0], lin);  lin = fmaf(a0.y, ewc[1], lin);
        lin = fmaf(a0.z, ewc[2], lin);  lin = fmaf(a0.w, ewc[3], lin);
        lin = fmaf(a1.x, ewc[4], lin);  lin = fmaf(a1.y, ewc[5], lin);
        lin = fmaf(a1.z, ewc[6], lin);  lin = fmaf(a1.w, ewc[7], lin);
        lin = fmaf(a2.x, ewc[8], lin);  lin = fmaf(a2.y, ewc[9], lin);
        lin = fmaf(a2.z, ewc[10], lin); lin = fmaf(a2.w, ewc[11], lin);
        lin = fmaf(a3.x, ewc[12], lin); lin = fmaf(a3.y, ewc[13], lin);
        lin = fmaf(a3.z, ewc[14], lin); lin = fmaf(a3.w, ewc[15], lin);
        acc += fmaxf(hs + lin, 0.0f);
    }
    A[n * HID + t] = acc;
}

// ==================== node MLP: 8 nodes/block + fused moment accumulation ====================
#define MLP_N 8
__global__ __launch_bounds__(HID) void k_mlp(
    const float* __restrict__ A, const int* __restrict__ batch,
    const float* __restrict__ w1, const float* __restrict__ b1,
    const float* __restrict__ w2, const float* __restrict__ b2,
    float* __restrict__ H, float* __restrict__ gsum, float* __restrict__ gsq) {
    __shared__ float h1s[MLP_N * HID];
    int n0 = blockIdx.x * MLP_N;
    int t = threadIdx.x;
    float acc[MLP_N];
    float bb = b1[t];
    #pragma unroll
    for (int i = 0; i < MLP_N; ++i) acc[i] = bb;
    for (int k4 = 0; k4 < HID; k4 += 4) {
        float4 a[MLP_N];
        #pragma unroll
        for (int i = 0; i < MLP_N; ++i)
            a[i] = *(const float4*)&A[(n0 + i) * HID + k4];
        #pragma unroll
        for (int kk = 0; kk < 4; ++kk) {
            float w = w1[(k4 + kk) * HID + t];
            #pragma unroll
            for (int i = 0; i < MLP_N; ++i)
                acc[i] = fmaf(((const float*)&a[i])[kk], w, acc[i]);
        }
    }
    #pragma unroll
    for (int i = 0; i < MLP_N; ++i) h1s[i * HID + t] = fmaxf(acc[i], 0.0f);
    __syncthreads();
    float bb2 = b2[t];
    #pragma unroll
    for (int i = 0; i < MLP_N; ++i) acc[i] = bb2;
    for (int k4 = 0; k4 < HID; k4 += 4) {
        float4 h[MLP_N];
        #pragma unroll
        for (int i = 0; i < MLP_N; ++i)
            h[i] = *(const float4*)&h1s[i * HID + k4];
        #pragma unroll
        for (int kk = 0; kk < 4; ++kk) {
            float w = w2[(k4 + kk) * HID + t];
            #pragma unroll
            for (int i = 0; i < MLP_N; ++i)
                acc[i] = fmaf(((const float*)&h[i])[kk], w, acc[i]);
        }
    }
    #pragma unroll
    for (int i = 0; i < MLP_N; ++i) H[(n0 + i) * HID + t] = acc[i];
    int g0 = batch[n0], g7 = batch[n0 + MLP_N - 1];
    if (g0 == g7) {
        float s = 0.0f, q = 0.0f;
        #pragma unroll
        for (int i = 0; i < MLP_N; ++i) { s += acc[i]; q += acc[i] * acc[i]; }
        atomicAdd(&gsum[g0 * HID + t], s);
        atomicAdd(&gsq[g0 * HID + t], q);
    } else {
        #pragma unroll
        for (int i = 0; i < MLP_N; ++i) {
            int g = batch[n0 + i];
            atomicAdd(&gsum[g * HID + t], acc[i]);
            atomicAdd(&gsq[g * HID + t], acc[i] * acc[i]);
        }
    }
}

// ==================== GraphNorm stats -> scale/offset (re-zeros moments for next layer) ====================
__global__ __launch_bounds__(HID) void k_stats(
    float* __restrict__ gsum, float* __restrict__ gsq,
    const float* __restrict__ cnt,
    const float* __restrict__ gw, const float* __restrict__ gb,
    const float* __restrict__ gms,
    float* __restrict__ sc, float* __restrict__ of) {
    int g = blockIdx.x;
    int t = threadIdx.x;
    float c = fmaxf(cnt[g], 1.0f);
    float mean = gsum[g * HID + t] / c;
    float msq  = gsq[g * HID + t] / c;
    float ms = gms[t];
    float var = msq - mean * mean * ms * (2.0f - ms);
    var = fmaxf(var, 0.0f);
    float istd = rsqrtf(var + EPS);
    float s = gw[t] * istd;
    sc[g * HID + t] = s;
    of[g * HID + t] = gb[t] - s * mean * ms;
    gsum[g * HID + t] = 0.0f;   // ready for next layer
    gsq[g * HID + t]  = 0.0f;
}

// ==================== normalize + relu (+ pooled global_add on last layer) ====================
__global__ __launch_bounds__(HID) void k_norm(
    float* __restrict__ H, const int* __restrict__ batch,
    const float* __restrict__ sc, const float* __restrict__ of,
    float* __restrict__ pool, int accumulate) {
    int n0 = blockIdx.x * MLP_N;
    int t = threadIdx.x;
    int g0 = batch[n0], g7 = batch[n0 + MLP_N - 1];
    if (g0 == g7) {
        float ssc = sc[g0 * HID + t], sof = of[g0 * HID + t];
        float ps = 0.0f;
        #pragma unroll
        for (int i = 0; i < MLP_N; ++i) {
            float v = fmaxf(H[(n0 + i) * HID + t] * ssc + sof, 0.0f);
            H[(n0 + i) * HID + t] = v;
            ps += v;
        }
        if (accumulate) atomicAdd(&pool[g0 * HID + t], ps);
    } else {
        #pragma unroll
        for (int i = 0; i < MLP_N; ++i) {
            int g = batch[n0 + i];
            float v = fmaxf(H[(n0 + i) * HID + t] * sc[g * HID + t] + of[g * HID + t], 0.0f);
            H[(n0 + i) * HID + t] = v;
            if (accumulate) atomicAdd(&pool[g * HID + t], v);
        }
    }
}

// ==================== output head ====================
__global__ __launch_bounds__(HID) void k_head(
    const float* __restrict__ pool,
    const float* __restrict__ fw1, const float* __restrict__ fb1,
    const float* __restrict__ fw2, const float* __restrict__ fb2,
    float* __restrict__ out) {
    __shared__ float ps[HID];
    __shared__ float red[2];
    int g = blockIdx.x;
    int t = threadIdx.x;
    ps[t] = pool[g * HID + t];
    __syncthreads();
    float acc = fb1[t];
    #pragma unroll 4
    for (int k = 0; k < HID; ++k) acc = fmaf(ps[k], fw1[k * HID + t], acc);
    float p = fmaxf(acc, 0.0f) * fw2[t];
    #pragma unroll
    for (int off = 32; off > 0; off >>= 1) p += __shfl_down(p, off, 64);
    if ((t & 63) == 0) red[t >> 6] = p;
    __syncthreads();
    if (t == 0) out[g] = red[0] + red[1] + fb2[0];
}

extern "C" void kernel_launch(void* const* d_in, const int* in_sizes, int n_in,
                              void* d_out, int out_size, void* d_ws, size_t ws_size,
                              hipStream_t stream) {
    const float* x     = (const float*)d_in[0];
    const int*   ei    = (const int*)d_in[1];
    const float* ea    = (const float*)d_in[2];
    const int*   batch = (const int*)d_in[3];
    const float* lw1 = (const float*)d_in[4];
    const float* lb1 = (const float*)d_in[5];
    const float* lw2 = (const float*)d_in[6];
    const float* lb2 = (const float*)d_in[7];
    const float* pw1 = (const float*)d_in[8];
    const float* pb1 = (const float*)d_in[9];
    const float* pw2 = (const float*)d_in[10];
    const float* pb2 = (const float*)d_in[11];
    const float* ew  = (const float*)d_in[12];
    const float* eb  = (const float*)d_in[13];
    const float* nw1 = (const float*)d_in[14];
    const float* nb1 = (const float*)d_in[15];
    const float* nw2 = (const float*)d_in[16];
    const float* nb2 = (const float*)d_in[17];
    const float* gw  = (const float*)d_in[18];
    const float* gb  = (const float*)d_in[19];
    const float* gms = (const float*)d_in[20];
    const float* fw1 = (const float*)d_in[21];
    const float* fb1 = (const float*)d_in[22];
    const float* fw2 = (const float*)d_in[23];
    const float* fb2 = (const float*)d_in[24];
    float* out = (float*)d_out;

    float* ws   = (float*)d_ws;
    float* H    = ws;                          // 6,400,000
    float* A    = H    + (size_t)N_NODES * HID;// 6,400,000
    float* gsum = A    + (size_t)N_NODES * HID;// 16384
    float* gsq  = gsum + NGRAPH * HID;
    float* sc   = gsq  + NGRAPH * HID;
    float* of   = sc   + NGRAPH * HID;
    float* pool = of   + NGRAPH * HID;
    float* cnt  = pool + NGRAPH * HID;         // 128
    int* row_cnt   = (int*)(cnt + NGRAPH);     // 50000
    int* row_start = row_cnt + N_NODES;        // 50000
    int* row_fill  = row_start + N_NODES;      // 50000
    int* partial   = row_fill + N_NODES;       // 128
    int* csr_eid   = partial + 128;            // 800000

    const int* srcs = ei;
    const int* dsts = ei + N_EDGES;

    // ---- init + CSR build (per call; graph fixed within a call) ----
    k_init<<<(N_NODES + 255) / 256, 256, 0, stream>>>(row_cnt, cnt, pool, gsum, gsq);
    k_count<<<(N_NODES + 255) / 256, 256, 0, stream>>>(batch, cnt);
    k_hist<<<(N_EDGES + 255) / 256, 256, 0, stream>>>(dsts, row_cnt);
    k_scan1<<<NCHUNK, 256, 0, stream>>>(row_cnt, partial);
    k_scan2<<<1, 128, 0, stream>>>(partial);
    k_scan3<<<NCHUNK, 512, 0, stream>>>(row_cnt, partial, row_start, row_fill);
    k_fill<<<(N_EDGES + 255) / 256, 256, 0, stream>>>(dsts, row_fill, csr_eid);

    // ---- encoder ----
    k_encoder<<<N_NODES / ENC_N, HID, 0, stream>>>(x, lw1, lb1, lw2, lb2,
                                                   pw1, pb1, pw2, pb2, H);

    // ---- layers ----
    for (int l = 0; l < NLAYERS; ++l) {
        k_gather<<<N_NODES, HID, 0, stream>>>(
            srcs, ea, row_start, row_fill, csr_eid,
            ew + l * EDGE_DIM * HID, eb + l * HID, H, A);
        k_mlp<<<N_NODES / MLP_N, HID, 0, stream>>>(
            A, batch, nw1 + l * HID * HID, nb1 + l * HID,
            nw2 + l * HID * HID, nb2 + l * HID, H, gsum, gsq);
        k_stats<<<NGRAPH, HID, 0, stream>>>(gsum, gsq, cnt,
                                            gw + l * HID, gb + l * HID, gms + l * HID,
                                            sc, of);
        k_norm<<<N_NODES / MLP_N, HID, 0, stream>>>(
            H, batch, sc, of, pool, (l == NLAYERS - 1) ? 1 : 0);
    }
    k_head<<<NGRAPH, HID, 0, stream>>>(pool, fw1, fb1, fw2, fb2, out);
}

// Round 3
// 1156.434 us; speedup vs baseline: 2.3618x; 1.1146x over previous
//
#include <hip/hip_runtime.h>

#define N_NODES 50000
#define N_EDGES 800000
#define IN_DIM  64
#define EDGE_DIM 16
#define HID     128
#define NLAYERS 3
#define NGRAPH  128
#define EPS     1e-5f

// ==================== init: zero small buffers + CSR counters ====================
__global__ void k_init(int* __restrict__ row_cnt, float* __restrict__ cnt,
                       float* __restrict__ pool, float* __restrict__ gsum,
                       float* __restrict__ gsq) {
    int i = blockIdx.x * blockDim.x + threadIdx.x;
    if (i < N_NODES) row_cnt[i] = 0;
    if (i < NGRAPH * HID) { pool[i] = 0.0f; gsum[i] = 0.0f; gsq[i] = 0.0f; }
    if (i < NGRAPH) cnt[i] = 0.0f;
}

// ==================== per-graph node counts ====================
__global__ void k_count(const int* __restrict__ batch, float* __restrict__ cnt) {
    int i = blockIdx.x * blockDim.x + threadIdx.x;
    if (i < N_NODES) atomicAdd(&cnt[batch[i]], 1.0f);
}

// ==================== CSR build: histogram of dst ====================
__global__ void k_hist(const int* __restrict__ dsts, int* __restrict__ row_cnt) {
    int e = blockIdx.x * blockDim.x + threadIdx.x;
    if (e < N_EDGES) atomicAdd(&row_cnt[dsts[e]], 1);
}

// ==================== scan phase 1: per-512-chunk sums ====================
__global__ __launch_bounds__(256) void k_scan1(const int* __restrict__ row_cnt,
                                               int* __restrict__ partial) {
    __shared__ int s[256];
    int t = threadIdx.x, b = blockIdx.x;
    int i0 = b * 512 + t;
    int v = 0;
    if (i0 < N_NODES) v += row_cnt[i0];
    if (i0 + 256 < N_NODES) v += row_cnt[i0 + 256];
    s[t] = v; __syncthreads();
    for (int off = 128; off > 0; off >>= 1) {
        if (t < off) s[t] += s[t + off];
        __syncthreads();
    }
    if (t == 0) partial[b] = s[0];
}

// ==================== scan phase 2: exclusive scan of partials ====================
#define NCHUNK 98
__global__ __launch_bounds__(128) void k_scan2(int* __restrict__ partial) {
    __shared__ int s[128];
    int t = threadIdx.x;
    int v = (t < NCHUNK) ? partial[t] : 0;
    s[t] = v; __syncthreads();
    for (int off = 1; off < 128; off <<= 1) {
        int x = (t >= off) ? s[t - off] : 0;
        __syncthreads();
        s[t] += x;
        __syncthreads();
    }
    partial[t] = s[t] - v;   // exclusive
}

// ==================== scan phase 3: per-chunk exclusive scan -> row_start/row_fill ====================
__global__ __launch_bounds__(512) void k_scan3(const int* __restrict__ row_cnt,
                                               const int* __restrict__ partial,
                                               int* __restrict__ row_start,
                                               int* __restrict__ row_fill) {
    __shared__ int s[512];
    int t = threadIdx.x, b = blockIdx.x;
    int i = b * 512 + t;
    int v = (i < N_NODES) ? row_cnt[i] : 0;
    s[t] = v; __syncthreads();
    for (int off = 1; off < 512; off <<= 1) {
        int x = (t >= off) ? s[t - off] : 0;
        __syncthreads();
        s[t] += x;
        __syncthreads();
    }
    int excl = s[t] - v + partial[b];
    if (i < N_NODES) { row_start[i] = excl; row_fill[i] = excl; }
}

// ==================== CSR fill: writes eid AND src per slot ====================
__global__ void k_fill(const int* __restrict__ srcs, const int* __restrict__ dsts,
                       int* __restrict__ row_fill,
                       int* __restrict__ csr_eid, int* __restrict__ csr_src) {
    int e = blockIdx.x * blockDim.x + threadIdx.x;
    if (e < N_EDGES) {
        int p = atomicAdd(&row_fill[dsts[e]], 1);
        csr_eid[p] = e;
        csr_src[p] = srcs[e];
    }
}

// ==================== input encoder: 4 nodes/block, both paths, select at end ====================
#define ENC_N 4
__global__ __launch_bounds__(HID) void k_encoder(
    const float* __restrict__ x,
    const float* __restrict__ lw1, const float* __restrict__ lb1,
    const float* __restrict__ lw2, const float* __restrict__ lb2,
    const float* __restrict__ pw1, const float* __restrict__ pb1,
    const float* __restrict__ pw2, const float* __restrict__ pb2,
    float* __restrict__ H) {
    __shared__ float h1l[ENC_N * HID];
    __shared__ float h1p[ENC_N * HID];
    int n0 = blockIdx.x * ENC_N;
    int t = threadIdx.x;
    float accl[ENC_N], accp[ENC_N];
    float bl = lb1[t], bp = pb1[t];
    #pragma unroll
    for (int i = 0; i < ENC_N; ++i) { accl[i] = bl; accp[i] = bp; }
    for (int k4 = 0; k4 < IN_DIM; k4 += 4) {
        float4 a[ENC_N];
        #pragma unroll
        for (int i = 0; i < ENC_N; ++i)
            a[i] = *(const float4*)&x[(n0 + i) * IN_DIM + k4];
        #pragma unroll
        for (int kk = 0; kk < 4; ++kk) {
            float wl = lw1[(k4 + kk) * HID + t];
            float wp = pw1[(k4 + kk) * HID + t];
            #pragma unroll
            for (int i = 0; i < ENC_N; ++i) {
                float c = ((const float*)&a[i])[kk];
                accl[i] = fmaf(c, wl, accl[i]);
                accp[i] = fmaf(c, wp, accp[i]);
            }
        }
    }
    #pragma unroll
    for (int i = 0; i < ENC_N; ++i) {
        h1l[i * HID + t] = fmaxf(accl[i], 0.0f);
        h1p[i * HID + t] = fmaxf(accp[i], 0.0f);
    }
    __syncthreads();
    float bl2 = lb2[t], bp2 = pb2[t];
    #pragma unroll
    for (int i = 0; i < ENC_N; ++i) { accl[i] = bl2; accp[i] = bp2; }
    for (int k4 = 0; k4 < HID; k4 += 4) {
        float4 hl[ENC_N], hp[ENC_N];
        #pragma unroll
        for (int i = 0; i < ENC_N; ++i) {
            hl[i] = *(const float4*)&h1l[i * HID + k4];
            hp[i] = *(const float4*)&h1p[i * HID + k4];
        }
        #pragma unroll
        for (int kk = 0; kk < 4; ++kk) {
            float wl = lw2[(k4 + kk) * HID + t];
            float wp = pw2[(k4 + kk) * HID + t];
            #pragma unroll
            for (int i = 0; i < ENC_N; ++i) {
                accl[i] = fmaf(((const float*)&hl[i])[kk], wl, accl[i]);
                accp[i] = fmaf(((const float*)&hp[i])[kk], wp, accp[i]);
            }
        }
    }
    #pragma unroll
    for (int i = 0; i < ENC_N; ++i) {
        bool prot = x[(n0 + i) * IN_DIM + (IN_DIM - 1)] > 0.5f;
        float v = prot ? accp[i] : accl[i];
        H[(n0 + i) * HID + t] = fmaxf(v, 0.0f);
    }
}

// ==================== edge gather: one dst node/block, 4 edges in flight ====================
__global__ __launch_bounds__(HID) void k_gather(
    const int* __restrict__ csr_src, const int* __restrict__ csr_eid,
    const float* __restrict__ ea,
    const int* __restrict__ row_start, const int* __restrict__ row_end,
    const float* __restrict__ ew, const float* __restrict__ eb,
    const float* __restrict__ H, float* __restrict__ A) {
    int n = blockIdx.x;
    int t = threadIdx.x;
    float ewc[EDGE_DIM];
    #pragma unroll
    for (int k = 0; k < EDGE_DIM; ++k) ewc[k] = ew[k * HID + t];
    float ebv = eb[t];
    float acc = H[n * HID + t];
    int p  = __builtin_amdgcn_readfirstlane(row_start[n]);
    int pe = __builtin_amdgcn_readfirstlane(row_end[n]);
    // 4 edges in flight: indices -> SGPRs, ea via scalar pipe, 4 H-rows via vector pipe
    for (; p + 4 <= pe; p += 4) {
        int s0 = __builtin_amdgcn_readfirstlane(csr_src[p]);
        int s1 = __builtin_amdgcn_readfirstlane(csr_src[p + 1]);
        int s2 = __builtin_amdgcn_readfirstlane(csr_src[p + 2]);
        int s3 = __builtin_amdgcn_readfirstlane(csr_src[p + 3]);
        int e0 = __builtin_amdgcn_readfirstlane(csr_eid[p]);
        int e1 = __builtin_amdgcn_readfirstlane(csr_eid[p + 1]);
        int e2 = __builtin_amdgcn_readfirstlane(csr_eid[p + 2]);
        int e3 = __builtin_amdgcn_readfirstlane(csr_eid[p + 3]);
        float h0 = H[s0 * HID + t];
        float h1 = H[s1 * HID + t];
        float h2 = H[s2 * HID + t];
        float h3 = H[s3 * HID + t];
        const float* q0 = ea + (size_t)e0 * EDGE_DIM;
        const float* q1 = ea + (size_t)e1 * EDGE_DIM;
        const float* q2 = ea + (size_t)e2 * EDGE_DIM;
        const float* q3 = ea + (size_t)e3 * EDGE_DIM;
        float l0 = ebv, l1 = ebv, l2 = ebv, l3 = ebv;
        #pragma unroll
        for (int k = 0; k < EDGE_DIM; ++k) {
            l0 = fmaf(q0[k], ewc[k], l0);
            l1 = fmaf(q1[k], ewc[k], l1);
            l2 = fmaf(q2[k], ewc[k], l2);
            l3 = fmaf(q3[k], ewc[k], l3);
        }
        acc += fmaxf(h0 + l0, 0.0f);
        acc += fmaxf(h1 + l1, 0.0f);
        acc += fmaxf(h2 + l2, 0.0f);
        acc += fmaxf(h3 + l3, 0.0f);
    }
    for (; p < pe; ++p) {
        int s0 = __builtin_amdgcn_readfirstlane(csr_src[p]);
        int e0 = __builtin_amdgcn_readfirstlane(csr_eid[p]);
        float h0 = H[s0 * HID + t];
        const float* q0 = ea + (size_t)e0 * EDGE_DIM;
        float l0 = ebv;
        #pragma unroll
        for (int k = 0; k < EDGE_DIM; ++k) l0 = fmaf(q0[k], ewc[k], l0);
        acc += fmaxf(h0 + l0, 0.0f);
    }
    A[n * HID + t] = acc;
}

// ==================== node MLP: 16 nodes/block + fused moment accumulation ====================
#define MLP_N 16
__global__ __launch_bounds__(HID) void k_mlp(
    const float* __restrict__ A, const int* __restrict__ batch,
    const float* __restrict__ w1, const float* __restrict__ b1,
    const float* __restrict__ w2, const float* __restrict__ b2,
    float* __restrict__ H, float* __restrict__ gsum, float* __restrict__ gsq) {
    __shared__ float h1s[MLP_N * HID];
    int n0 = blockIdx.x * MLP_N;
    int t = threadIdx.x;
    float acc[MLP_N];
    float bb = b1[t];
    #pragma unroll
    for (int i = 0; i < MLP_N; ++i) acc[i] = bb;
    for (int k4 = 0; k4 < HID; k4 += 4) {
        float4 a[MLP_N];
        #pragma unroll
        for (int i = 0; i < MLP_N; ++i)
            a[i] = *(const float4*)&A[(n0 + i) * HID + k4];
        #pragma unroll
        for (int kk = 0; kk < 4; ++kk) {
            float w = w1[(k4 + kk) * HID + t];
            #pragma unroll
            for (int i = 0; i < MLP_N; ++i)
                acc[i] = fmaf(((const float*)&a[i])[kk], w, acc[i]);
        }
    }
    #pragma unroll
    for (int i = 0; i < MLP_N; ++i) h1s[i * HID + t] = fmaxf(acc[i], 0.0f);
    __syncthreads();
    float bb2 = b2[t];
    #pragma unroll
    for (int i = 0; i < MLP_N; ++i) acc[i] = bb2;
    for (int k4 = 0; k4 < HID; k4 += 4) {
        float4 h[MLP_N];
        #pragma unroll
        for (int i = 0; i < MLP_N; ++i)
            h[i] = *(const float4*)&h1s[i * HID + k4];
        #pragma unroll
        for (int kk = 0; kk < 4; ++kk) {
            float w = w2[(k4 + kk) * HID + t];
            #pragma unroll
            for (int i = 0; i < MLP_N; ++i)
                acc[i] = fmaf(((const float*)&h[i])[kk], w, acc[i]);
        }
    }
    #pragma unroll
    for (int i = 0; i < MLP_N; ++i) H[(n0 + i) * HID + t] = acc[i];
    int g0 = batch[n0], gN = batch[n0 + MLP_N - 1];
    if (g0 == gN) {
        float s = 0.0f, q = 0.0f;
        #pragma unroll
        for (int i = 0; i < MLP_N; ++i) { s += acc[i]; q += acc[i] * acc[i]; }
        atomicAdd(&gsum[g0 * HID + t], s);
        atomicAdd(&gsq[g0 * HID + t], q);
    } else {
        #pragma unroll
        for (int i = 0; i < MLP_N; ++i) {
            int g = batch[n0 + i];
            atomicAdd(&gsum[g * HID + t], acc[i]);
            atomicAdd(&gsq[g * HID + t], acc[i] * acc[i]);
        }
    }
}

// ==================== GraphNorm stats -> scale/offset (re-zeros moments) ====================
__global__ __launch_bounds__(HID) void k_stats(
    float* __restrict__ gsum, float* __restrict__ gsq,
    const float* __restrict__ cnt,
    const float* __restrict__ gw, const float* __restrict__ gb,
    const float* __restrict__ gms,
    float* __restrict__ sc, float* __restrict__ of) {
    int g = blockIdx.x;
    int t = threadIdx.x;
    float c = fmaxf(cnt[g], 1.0f);
    float mean = gsum[g * HID + t] / c;
    float msq  = gsq[g * HID + t] / c;
    float ms = gms[t];
    float var = msq - mean * mean * ms * (2.0f - ms);
    var = fmaxf(var, 0.0f);
    float istd = rsqrtf(var + EPS);
    float s = gw[t] * istd;
    sc[g * HID + t] = s;
    of[g * HID + t] = gb[t] - s * mean * ms;
    gsum[g * HID + t] = 0.0f;
    gsq[g * HID + t]  = 0.0f;
}

// ==================== normalize + relu (+ pooled global_add on last layer) ====================
#define NORM_N 8
__global__ __launch_bounds__(HID) void k_norm(
    float* __restrict__ H, const int* __restrict__ batch,
    const float* __restrict__ sc, const float* __restrict__ of,
    float* __restrict__ pool, int accumulate) {
    int n0 = blockIdx.x * NORM_N;
    int t = threadIdx.x;
    int g0 = batch[n0], gN = batch[n0 + NORM_N - 1];
    if (g0 == gN) {
        float ssc = sc[g0 * HID + t], sof = of[g0 * HID + t];
        float ps = 0.0f;
        #pragma unroll
        for (int i = 0; i < NORM_N; ++i) {
            float v = fmaxf(H[(n0 + i) * HID + t] * ssc + sof, 0.0f);
            H[(n0 + i) * HID + t] = v;
            ps += v;
        }
        if (accumulate) atomicAdd(&pool[g0 * HID + t], ps);
    } else {
        #pragma unroll
        for (int i = 0; i < NORM_N; ++i) {
            int g = batch[n0 + i];
            float v = fmaxf(H[(n0 + i) * HID + t] * sc[g * HID + t] + of[g * HID + t], 0.0f);
            H[(n0 + i) * HID + t] = v;
            if (accumulate) atomicAdd(&pool[g * HID + t], v);
        }
    }
}

// ==================== output head ====================
__global__ __launch_bounds__(HID) void k_head(
    const float* __restrict__ pool,
    const float* __restrict__ fw1, const float* __restrict__ fb1,
    const float* __restrict__ fw2, const float* __restrict__ fb2,
    float* __restrict__ out) {
    __shared__ float ps[HID];
    __shared__ float red[2];
    int g = blockIdx.x;
    int t = threadIdx.x;
    ps[t] = pool[g * HID + t];
    __syncthreads();
    float acc = fb1[t];
    #pragma unroll 4
    for (int k = 0; k < HID; ++k) acc = fmaf(ps[k], fw1[k * HID + t], acc);
    float p = fmaxf(acc, 0.0f) * fw2[t];
    #pragma unroll
    for (int off = 32; off > 0; off >>= 1) p += __shfl_down(p, off, 64);
    if ((t & 63) == 0) red[t >> 6] = p;
    __syncthreads();
    if (t == 0) out[g] = red[0] + red[1] + fb2[0];
}

extern "C" void kernel_launch(void* const* d_in, const int* in_sizes, int n_in,
                              void* d_out, int out_size, void* d_ws, size_t ws_size,
                              hipStream_t stream) {
    const float* x     = (const float*)d_in[0];
    const int*   ei    = (const int*)d_in[1];
    const float* ea    = (const float*)d_in[2];
    const int*   batch = (const int*)d_in[3];
    const float* lw1 = (const float*)d_in[4];
    const float* lb1 = (const float*)d_in[5];
    const float* lw2 = (const float*)d_in[6];
    const float* lb2 = (const float*)d_in[7];
    const float* pw1 = (const float*)d_in[8];
    const float* pb1 = (const float*)d_in[9];
    const float* pw2 = (const float*)d_in[10];
    const float* pb2 = (const float*)d_in[11];
    const float* ew  = (const float*)d_in[12];
    const float* eb  = (const float*)d_in[13];
    const float* nw1 = (const float*)d_in[14];
    const float* nb1 = (const float*)d_in[15];
    const float* nw2 = (const float*)d_in[16];
    const float* nb2 = (const float*)d_in[17];
    const float* gw  = (const float*)d_in[18];
    const float* gb  = (const float*)d_in[19];
    const float* gms = (const float*)d_in[20];
    const float* fw1 = (const float*)d_in[21];
    const float* fb1 = (const float*)d_in[22];
    const float* fw2 = (const float*)d_in[23];
    const float* fb2 = (const float*)d_in[24];
    float* out = (float*)d_out;

    float* ws   = (float*)d_ws;
    float* H    = ws;                          // 6,400,000
    float* A    = H    + (size_t)N_NODES * HID;// 6,400,000
    float* gsum = A    + (size_t)N_NODES * HID;
    float* gsq  = gsum + NGRAPH * HID;
    float* sc   = gsq  + NGRAPH * HID;
    float* of   = sc   + NGRAPH * HID;
    float* pool = of   + NGRAPH * HID;
    float* cnt  = pool + NGRAPH * HID;         // 128
    int* row_cnt   = (int*)(cnt + NGRAPH);     // 50000
    int* row_start = row_cnt + N_NODES;        // 50000
    int* row_fill  = row_start + N_NODES;      // 50000
    int* partial   = row_fill + N_NODES;       // 128
    int* csr_eid   = partial + 128;            // 800000
    int* csr_src   = csr_eid + N_EDGES;        // 800000

    const int* srcs = ei;
    const int* dsts = ei + N_EDGES;

    // ---- init + CSR build ----
    k_init<<<(N_NODES + 255) / 256, 256, 0, stream>>>(row_cnt, cnt, pool, gsum, gsq);
    k_count<<<(N_NODES + 255) / 256, 256, 0, stream>>>(batch, cnt);
    k_hist<<<(N_EDGES + 255) / 256, 256, 0, stream>>>(dsts, row_cnt);
    k_scan1<<<NCHUNK, 256, 0, stream>>>(row_cnt, partial);
    k_scan2<<<1, 128, 0, stream>>>(partial);
    k_scan3<<<NCHUNK, 512, 0, stream>>>(row_cnt, partial, row_start, row_fill);
    k_fill<<<(N_EDGES + 255) / 256, 256, 0, stream>>>(srcs, dsts, row_fill, csr_eid, csr_src);

    // ---- encoder ----
    k_encoder<<<N_NODES / ENC_N, HID, 0, stream>>>(x, lw1, lb1, lw2, lb2,
                                                   pw1, pb1, pw2, pb2, H);

    // ---- layers ----
    for (int l = 0; l < NLAYERS; ++l) {
        k_gather<<<N_NODES, HID, 0, stream>>>(
            csr_src, csr_eid, ea, row_start, row_fill,
            ew + l * EDGE_DIM * HID, eb + l * HID, H, A);
        k_mlp<<<N_NODES / MLP_N, HID, 0, stream>>>(
            A, batch, nw1 + l * HID * HID, nb1 + l * HID,
            nw2 + l * HID * HID, nb2 + l * HID, H, gsum, gsq);
        k_stats<<<NGRAPH, HID, 0, stream>>>(gsum, gsq, cnt,
                                            gw + l * HID, gb + l * HID, gms + l * HID,
                                            sc, of);
        k_norm<<<N_NODES / NORM_N, HID, 0, stream>>>(
            H, batch, sc, of, pool, (l == NLAYERS - 1) ? 1 : 0);
    }
    k_head<<<NGRAPH, HID, 0, stream>>>(pool, fw1, fb1, fw2, fb2, out);
}

// Round 4
// 987.063 us; speedup vs baseline: 2.7671x; 1.1716x over previous
//
#include <hip/hip_runtime.h>

#define N_NODES 50000
#define N_EDGES 800000
#define IN_DIM  64
#define EDGE_DIM 16
#define HID     128
#define NLAYERS 3
#define NGRAPH  128
#define EPS     1e-5f

// ==================== init: zero small buffers + CSR counters ====================
__global__ void k_init(int* __restrict__ row_cnt, float* __restrict__ pool,
                       float* __restrict__ gsum, float* __restrict__ gsq) {
    int i = blockIdx.x * blockDim.x + threadIdx.x;
    if (i < N_NODES) row_cnt[i] = 0;
    if (i < NGRAPH * HID) { pool[i] = 0.0f; gsum[i] = 0.0f; gsq[i] = 0.0f; }
}

// ==================== per-graph node counts via binary search (batch is sorted) ====================
__global__ __launch_bounds__(NGRAPH) void k_count(const int* __restrict__ batch,
                                                  float* __restrict__ cnt) {
    int g = threadIdx.x;
    // lower_bound(g) and lower_bound(g+1)
    int lo = 0, hi = N_NODES;
    while (lo < hi) { int mid = (lo + hi) >> 1; if (batch[mid] < g) lo = mid + 1; else hi = mid; }
    int a = lo;
    lo = 0; hi = N_NODES;
    while (lo < hi) { int mid = (lo + hi) >> 1; if (batch[mid] < g + 1) lo = mid + 1; else hi = mid; }
    cnt[g] = (float)(lo - a);
}

// ==================== CSR build: histogram of dst ====================
__global__ void k_hist(const int* __restrict__ dsts, int* __restrict__ row_cnt) {
    int e = blockIdx.x * blockDim.x + threadIdx.x;
    if (e < N_EDGES) atomicAdd(&row_cnt[dsts[e]], 1);
}

// ==================== scan phase 1: per-512-chunk sums ====================
__global__ __launch_bounds__(256) void k_scan1(const int* __restrict__ row_cnt,
                                               int* __restrict__ partial) {
    __shared__ int s[256];
    int t = threadIdx.x, b = blockIdx.x;
    int i0 = b * 512 + t;
    int v = 0;
    if (i0 < N_NODES) v += row_cnt[i0];
    if (i0 + 256 < N_NODES) v += row_cnt[i0 + 256];
    s[t] = v; __syncthreads();
    for (int off = 128; off > 0; off >>= 1) {
        if (t < off) s[t] += s[t + off];
        __syncthreads();
    }
    if (t == 0) partial[b] = s[0];
}

// ==================== scan phase 2: exclusive scan of partials ====================
#define NCHUNK 98
__global__ __launch_bounds__(128) void k_scan2(int* __restrict__ partial) {
    __shared__ int s[128];
    int t = threadIdx.x;
    int v = (t < NCHUNK) ? partial[t] : 0;
    s[t] = v; __syncthreads();
    for (int off = 1; off < 128; off <<= 1) {
        int x = (t >= off) ? s[t - off] : 0;
        __syncthreads();
        s[t] += x;
        __syncthreads();
    }
    partial[t] = s[t] - v;   // exclusive
}

// ==================== scan phase 3: per-chunk exclusive scan -> row_start/row_fill ====================
__global__ __launch_bounds__(512) void k_scan3(const int* __restrict__ row_cnt,
                                               const int* __restrict__ partial,
                                               int* __restrict__ row_start,
                                               int* __restrict__ row_fill) {
    __shared__ int s[512];
    int t = threadIdx.x, b = blockIdx.x;
    int i = b * 512 + t;
    int v = (i < N_NODES) ? row_cnt[i] : 0;
    s[t] = v; __syncthreads();
    for (int off = 1; off < 512; off <<= 1) {
        int x = (t >= off) ? s[t - off] : 0;
        __syncthreads();
        s[t] += x;
        __syncthreads();
    }
    int excl = s[t] - v + partial[b];
    if (i < N_NODES) { row_start[i] = excl; row_fill[i] = excl; }
}

// ==================== CSR fill: writes eid AND src per slot ====================
__global__ void k_fill(const int* __restrict__ srcs, const int* __restrict__ dsts,
                       int* __restrict__ row_fill,
                       int* __restrict__ csr_eid, int* __restrict__ csr_src) {
    int e = blockIdx.x * blockDim.x + threadIdx.x;
    if (e < N_EDGES) {
        int p = atomicAdd(&row_fill[dsts[e]], 1);
        csr_eid[p] = e;
        csr_src[p] = srcs[e];
    }
}

// ==================== input encoder: 4 nodes/block, both paths, select at end ====================
#define ENC_N 4
__global__ __launch_bounds__(HID) void k_encoder(
    const float* __restrict__ x,
    const float* __restrict__ lw1, const float* __restrict__ lb1,
    const float* __restrict__ lw2, const float* __restrict__ lb2,
    const float* __restrict__ pw1, const float* __restrict__ pb1,
    const float* __restrict__ pw2, const float* __restrict__ pb2,
    float* __restrict__ H) {
    __shared__ float h1l[ENC_N * HID];
    __shared__ float h1p[ENC_N * HID];
    int n0 = blockIdx.x * ENC_N;
    int t = threadIdx.x;
    float accl[ENC_N], accp[ENC_N];
    float bl = lb1[t], bp = pb1[t];
    #pragma unroll
    for (int i = 0; i < ENC_N; ++i) { accl[i] = bl; accp[i] = bp; }
    for (int k4 = 0; k4 < IN_DIM; k4 += 4) {
        float4 a[ENC_N];
        #pragma unroll
        for (int i = 0; i < ENC_N; ++i)
            a[i] = *(const float4*)&x[(n0 + i) * IN_DIM + k4];
        #pragma unroll
        for (int kk = 0; kk < 4; ++kk) {
            float wl = lw1[(k4 + kk) * HID + t];
            float wp = pw1[(k4 + kk) * HID + t];
            #pragma unroll
            for (int i = 0; i < ENC_N; ++i) {
                float c = ((const float*)&a[i])[kk];
                accl[i] = fmaf(c, wl, accl[i]);
                accp[i] = fmaf(c, wp, accp[i]);
            }
        }
    }
    #pragma unroll
    for (int i = 0; i < ENC_N; ++i) {
        h1l[i * HID + t] = fmaxf(accl[i], 0.0f);
        h1p[i * HID + t] = fmaxf(accp[i], 0.0f);
    }
    __syncthreads();
    float bl2 = lb2[t], bp2 = pb2[t];
    #pragma unroll
    for (int i = 0; i < ENC_N; ++i) { accl[i] = bl2; accp[i] = bp2; }
    for (int k4 = 0; k4 < HID; k4 += 4) {
        float4 hl[ENC_N], hp[ENC_N];
        #pragma unroll
        for (int i = 0; i < ENC_N; ++i) {
            hl[i] = *(const float4*)&h1l[i * HID + k4];
            hp[i] = *(const float4*)&h1p[i * HID + k4];
        }
        #pragma unroll
        for (int kk = 0; kk < 4; ++kk) {
            float wl = lw2[(k4 + kk) * HID + t];
            float wp = pw2[(k4 + kk) * HID + t];
            #pragma unroll
            for (int i = 0; i < ENC_N; ++i) {
                accl[i] = fmaf(((const float*)&hl[i])[kk], wl, accl[i]);
                accp[i] = fmaf(((const float*)&hp[i])[kk], wp, accp[i]);
            }
        }
    }
    #pragma unroll
    for (int i = 0; i < ENC_N; ++i) {
        bool prot = x[(n0 + i) * IN_DIM + (IN_DIM - 1)] > 0.5f;
        float v = prot ? accp[i] : accl[i];
        H[(n0 + i) * HID + t] = fmaxf(v, 0.0f);
    }
}

// ==================== edge gather v3: one wave per node, float2 lanes, 8 edges in flight ====================
__global__ __launch_bounds__(HID) void k_gather(
    const int* __restrict__ csr_src, const int* __restrict__ csr_eid,
    const float* __restrict__ ea,
    const int* __restrict__ row_start, const int* __restrict__ row_end,
    const float* __restrict__ ew, const float* __restrict__ eb,
    const float* __restrict__ H, float* __restrict__ A) {
    int wave = threadIdx.x >> 6;          // 0 or 1
    int l    = threadIdx.x & 63;          // lane
    int n = blockIdx.x * 2 + wave;        // node for this wave
    int f = l * 2;                        // feature pair owned by this lane
    float2 ewc[EDGE_DIM];
    #pragma unroll
    for (int k = 0; k < EDGE_DIM; ++k)
        ewc[k] = *(const float2*)&ew[k * HID + f];
    float2 ebv = *(const float2*)&eb[f];
    float2 acc = *(const float2*)&H[n * HID + f];
    int p  = __builtin_amdgcn_readfirstlane(row_start[n]);
    int pe = __builtin_amdgcn_readfirstlane(row_end[n]);
    // 8 edges in flight
    for (; p + 8 <= pe; p += 8) {
        int s[8], e[8];
        #pragma unroll
        for (int j = 0; j < 8; ++j) {
            s[j] = __builtin_amdgcn_readfirstlane(csr_src[p + j]);
            e[j] = __builtin_amdgcn_readfirstlane(csr_eid[p + j]);
        }
        float2 h[8];
        #pragma unroll
        for (int j = 0; j < 8; ++j)
            h[j] = *(const float2*)&H[s[j] * HID + f];
        #pragma unroll
        for (int j = 0; j < 8; ++j) {
            const float* q = ea + (size_t)e[j] * EDGE_DIM;
            float2 lin = ebv;
            #pragma unroll
            for (int k = 0; k < EDGE_DIM; ++k) {
                lin.x = fmaf(q[k], ewc[k].x, lin.x);
                lin.y = fmaf(q[k], ewc[k].y, lin.y);
            }
            acc.x += fmaxf(h[j].x + lin.x, 0.0f);
            acc.y += fmaxf(h[j].y + lin.y, 0.0f);
        }
    }
    for (; p < pe; ++p) {
        int s0 = __builtin_amdgcn_readfirstlane(csr_src[p]);
        int e0 = __builtin_amdgcn_readfirstlane(csr_eid[p]);
        float2 h0 = *(const float2*)&H[s0 * HID + f];
        const float* q = ea + (size_t)e0 * EDGE_DIM;
        float2 lin = ebv;
        #pragma unroll
        for (int k = 0; k < EDGE_DIM; ++k) {
            lin.x = fmaf(q[k], ewc[k].x, lin.x);
            lin.y = fmaf(q[k], ewc[k].y, lin.y);
        }
        acc.x += fmaxf(h0.x + lin.x, 0.0f);
        acc.y += fmaxf(h0.y + lin.y, 0.0f);
    }
    *(float2*)&A[n * HID + f] = acc;
}

// ==================== node MLP: 16 nodes/block + fused moment accumulation ====================
#define MLP_N 16
__global__ __launch_bounds__(HID) void k_mlp(
    const float* __restrict__ A, const int* __restrict__ batch,
    const float* __restrict__ w1, const float* __restrict__ b1,
    const float* __restrict__ w2, const float* __restrict__ b2,
    float* __restrict__ H, float* __restrict__ gsum, float* __restrict__ gsq) {
    __shared__ float h1s[MLP_N * HID];
    int n0 = blockIdx.x * MLP_N;
    int t = threadIdx.x;
    float acc[MLP_N];
    float bb = b1[t];
    #pragma unroll
    for (int i = 0; i < MLP_N; ++i) acc[i] = bb;
    for (int k4 = 0; k4 < HID; k4 += 4) {
        float4 a[MLP_N];
        #pragma unroll
        for (int i = 0; i < MLP_N; ++i)
            a[i] = *(const float4*)&A[(n0 + i) * HID + k4];
        #pragma unroll
        for (int kk = 0; kk < 4; ++kk) {
            float w = w1[(k4 + kk) * HID + t];
            #pragma unroll
            for (int i = 0; i < MLP_N; ++i)
                acc[i] = fmaf(((const float*)&a[i])[kk], w, acc[i]);
        }
    }
    #pragma unroll
    for (int i = 0; i < MLP_N; ++i) h1s[i * HID + t] = fmaxf(acc[i], 0.0f);
    __syncthreads();
    float bb2 = b2[t];
    #pragma unroll
    for (int i = 0; i < MLP_N; ++i) acc[i] = bb2;
    for (int k4 = 0; k4 < HID; k4 += 4) {
        float4 h[MLP_N];
        #pragma unroll
        for (int i = 0; i < MLP_N; ++i)
            h[i] = *(const float4*)&h1s[i * HID + k4];
        #pragma unroll
        for (int kk = 0; kk < 4; ++kk) {
            float w = w2[(k4 + kk) * HID + t];
            #pragma unroll
            for (int i = 0; i < MLP_N; ++i)
                acc[i] = fmaf(((const float*)&h[i])[kk], w, acc[i]);
        }
    }
    #pragma unroll
    for (int i = 0; i < MLP_N; ++i) H[(n0 + i) * HID + t] = acc[i];
    int g0 = batch[n0], gN = batch[n0 + MLP_N - 1];
    if (g0 == gN) {
        float s = 0.0f, q = 0.0f;
        #pragma unroll
        for (int i = 0; i < MLP_N; ++i) { s += acc[i]; q += acc[i] * acc[i]; }
        atomicAdd(&gsum[g0 * HID + t], s);
        atomicAdd(&gsq[g0 * HID + t], q);
    } else {
        #pragma unroll
        for (int i = 0; i < MLP_N; ++i) {
            int g = batch[n0 + i];
            atomicAdd(&gsum[g * HID + t], acc[i]);
            atomicAdd(&gsq[g * HID + t], acc[i] * acc[i]);
        }
    }
}

// ==================== GraphNorm stats -> scale/offset (re-zeros moments) ====================
__global__ __launch_bounds__(HID) void k_stats(
    float* __restrict__ gsum, float* __restrict__ gsq,
    const float* __restrict__ cnt,
    const float* __restrict__ gw, const float* __restrict__ gb,
    const float* __restrict__ gms,
    float* __restrict__ sc, float* __restrict__ of) {
    int g = blockIdx.x;
    int t = threadIdx.x;
    float c = fmaxf(cnt[g], 1.0f);
    float mean = gsum[g * HID + t] / c;
    float msq  = gsq[g * HID + t] / c;
    float ms = gms[t];
    float var = msq - mean * mean * ms * (2.0f - ms);
    var = fmaxf(var, 0.0f);
    float istd = rsqrtf(var + EPS);
    float s = gw[t] * istd;
    sc[g * HID + t] = s;
    of[g * HID + t] = gb[t] - s * mean * ms;
    gsum[g * HID + t] = 0.0f;
    gsq[g * HID + t]  = 0.0f;
}

// ==================== normalize + relu (+ pooled global_add on last layer) ====================
#define NORM_N 8
__global__ __launch_bounds__(HID) void k_norm(
    float* __restrict__ H, const int* __restrict__ batch,
    const float* __restrict__ sc, const float* __restrict__ of,
    float* __restrict__ pool, int accumulate) {
    int n0 = blockIdx.x * NORM_N;
    int t = threadIdx.x;
    int g0 = batch[n0], gN = batch[n0 + NORM_N - 1];
    if (g0 == gN) {
        float ssc = sc[g0 * HID + t], sof = of[g0 * HID + t];
        float ps = 0.0f;
        #pragma unroll
        for (int i = 0; i < NORM_N; ++i) {
            float v = fmaxf(H[(n0 + i) * HID + t] * ssc + sof, 0.0f);
            H[(n0 + i) * HID + t] = v;
            ps += v;
        }
        if (accumulate) atomicAdd(&pool[g0 * HID + t], ps);
    } else {
        #pragma unroll
        for (int i = 0; i < NORM_N; ++i) {
            int g = batch[n0 + i];
            float v = fmaxf(H[(n0 + i) * HID + t] * sc[g * HID + t] + of[g * HID + t], 0.0f);
            H[(n0 + i) * HID + t] = v;
            if (accumulate) atomicAdd(&pool[g * HID + t], v);
        }
    }
}

// ==================== output head ====================
__global__ __launch_bounds__(HID) void k_head(
    const float* __restrict__ pool,
    const float* __restrict__ fw1, const float* __restrict__ fb1,
    const float* __restrict__ fw2, const float* __restrict__ fb2,
    float* __restrict__ out) {
    __shared__ float ps[HID];
    __shared__ float red[2];
    int g = blockIdx.x;
    int t = threadIdx.x;
    ps[t] = pool[g * HID + t];
    __syncthreads();
    float acc = fb1[t];
    #pragma unroll 4
    for (int k = 0; k < HID; ++k) acc = fmaf(ps[k], fw1[k * HID + t], acc);
    float p = fmaxf(acc, 0.0f) * fw2[t];
    #pragma unroll
    for (int off = 32; off > 0; off >>= 1) p += __shfl_down(p, off, 64);
    if ((t & 63) == 0) red[t >> 6] = p;
    __syncthreads();
    if (t == 0) out[g] = red[0] + red[1] + fb2[0];
}

extern "C" void kernel_launch(void* const* d_in, const int* in_sizes, int n_in,
                              void* d_out, int out_size, void* d_ws, size_t ws_size,
                              hipStream_t stream) {
    const float* x     = (const float*)d_in[0];
    const int*   ei    = (const int*)d_in[1];
    const float* ea    = (const float*)d_in[2];
    const int*   batch = (const int*)d_in[3];
    const float* lw1 = (const float*)d_in[4];
    const float* lb1 = (const float*)d_in[5];
    const float* lw2 = (const float*)d_in[6];
    const float* lb2 = (const float*)d_in[7];
    const float* pw1 = (const float*)d_in[8];
    const float* pb1 = (const float*)d_in[9];
    const float* pw2 = (const float*)d_in[10];
    const float* pb2 = (const float*)d_in[11];
    const float* ew  = (const float*)d_in[12];
    const float* eb  = (const float*)d_in[13];
    const float* nw1 = (const float*)d_in[14];
    const float* nb1 = (const float*)d_in[15];
    const float* nw2 = (const float*)d_in[16];
    const float* nb2 = (const float*)d_in[17];
    const float* gw  = (const float*)d_in[18];
    const float* gb  = (const float*)d_in[19];
    const float* gms = (const float*)d_in[20];
    const float* fw1 = (const float*)d_in[21];
    const float* fb1 = (const float*)d_in[22];
    const float* fw2 = (const float*)d_in[23];
    const float* fb2 = (const float*)d_in[24];
    float* out = (float*)d_out;

    float* ws   = (float*)d_ws;
    float* H    = ws;                          // 6,400,000
    float* A    = H    + (size_t)N_NODES * HID;// 6,400,000
    float* gsum = A    + (size_t)N_NODES * HID;
    float* gsq  = gsum + NGRAPH * HID;
    float* sc   = gsq  + NGRAPH * HID;
    float* of   = sc   + NGRAPH * HID;
    float* pool = of   + NGRAPH * HID;
    float* cnt  = pool + NGRAPH * HID;         // 128
    int* row_cnt   = (int*)(cnt + NGRAPH);     // 50000
    int* row_start = row_cnt + N_NODES;        // 50000
    int* row_fill  = row_start + N_NODES;      // 50000
    int* partial   = row_fill + N_NODES;       // 128
    int* csr_eid   = partial + 128;            // 800000
    int* csr_src   = csr_eid + N_EDGES;        // 800000

    const int* srcs = ei;
    const int* dsts = ei + N_EDGES;

    // ---- init + CSR build ----
    k_init<<<(N_NODES + 255) / 256, 256, 0, stream>>>(row_cnt, pool, gsum, gsq);
    k_count<<<1, NGRAPH, 0, stream>>>(batch, cnt);
    k_hist<<<(N_EDGES + 255) / 256, 256, 0, stream>>>(dsts, row_cnt);
    k_scan1<<<NCHUNK, 256, 0, stream>>>(row_cnt, partial);
    k_scan2<<<1, 128, 0, stream>>>(partial);
    k_scan3<<<NCHUNK, 512, 0, stream>>>(row_cnt, partial, row_start, row_fill);
    k_fill<<<(N_EDGES + 255) / 256, 256, 0, stream>>>(srcs, dsts, row_fill, csr_eid, csr_src);

    // ---- encoder ----
    k_encoder<<<N_NODES / ENC_N, HID, 0, stream>>>(x, lw1, lb1, lw2, lb2,
                                                   pw1, pb1, pw2, pb2, H);

    // ---- layers ----
    for (int l = 0; l < NLAYERS; ++l) {
        k_gather<<<N_NODES / 2, HID, 0, stream>>>(
            csr_src, csr_eid, ea, row_start, row_fill,
            ew + l * EDGE_DIM * HID, eb + l * HID, H, A);
        k_mlp<<<N_NODES / MLP_N, HID, 0, stream>>>(
            A, batch, nw1 + l * HID * HID, nb1 + l * HID,
            nw2 + l * HID * HID, nb2 + l * HID, H, gsum, gsq);
        k_stats<<<NGRAPH, HID, 0, stream>>>(gsum, gsq, cnt,
                                            gw + l * HID, gb + l * HID, gms + l * HID,
                                            sc, of);
        k_norm<<<N_NODES / NORM_N, HID, 0, stream>>>(
            H, batch, sc, of, pool, (l == NLAYERS - 1) ? 1 : 0);
    }
    k_head<<<NGRAPH, HID, 0, stream>>>(pool, fw1, fb1, fw2, fb2, out);
}